// Round 7
// baseline (1572.096 us; speedup 1.0000x reference)
//
#include <hip/hip_runtime.h>

// LightGCN propagation, MI355X. Round 11.
// R10 evidence: all build kernels <87.5us (absent from top-5); spmm item hit
// rate 33% == L2(4MB)/footprint(12.8MB), user 62% == 4/6.4 -> hit rate is
// concurrent-footprint-determined. Compulsory floor = table x 8 XCD.
// R11: source-tiled spmm. col sorted by (row, src>>14) in phase2 (2048-bin
// counting sort, emits bnd[row*8+t]; row[] eliminated). Spmm = co-resident
// grid (512x512, launch_bounds(512,4) -> <=128 VGPR -> 2 blk/CU guaranteed),
// 13-25 rows/wave with reg accumulators, tiles outermost, bounded-spin grid
// barrier between tiles (perf-only: timeout degrades locality, never
// correctness). Per phase each XCD re-reads only the 2MB tile -> gather
// misses ~= compulsory (item 299->~125MB).
// Tiers: T2 (h0+h1+bnd in ws, 68.8MB) / T1 (h1+bnd in ws, h0 in u2, 49.6MB)
// / B (bnd only: untiled fp16 L1 + f32 L2, 30.4MB) / C atomic push.
//
// Inputs: [0] user_emb0 [100000,64] f32, [1] item_emb0 [50000,64] f32,
// [2] a_ui_vals [E] f32 (unused; ==1/deg_u), [3] a_iu_vals [E] f32 (unused),
// [4] edge_u [E] i32, [5] edge_i [E] i32.
// Output: user_layers [3,100000,64] then item_layers [3,50000,64], f32 flat.

constexpr int N_USERS = 100000;
constexpr int N_ITEMS = 50000;
constexpr int N_ROWS  = N_USERS + N_ITEMS;   // combined CSR rows
constexpr int D = 64;
constexpr int E_EDGES = 3200000;
constexpr float ALPHA = 0.1f;

constexpr long long NUF = (long long)N_USERS * D;  // 6,400,000
constexpr long long NIF = (long long)N_ITEMS * D;  // 3,200,000

// super-buckets: 256 combined rows each
constexpr int SB_SHIFT = 8;
constexpr int SB_ROWS  = 1 << SB_SHIFT;                       // 256
constexpr int NSB      = (N_ROWS + SB_ROWS - 1) >> SB_SHIFT;  // 586
constexpr int CAP      = 20480;  // static slots per bucket; worst count ~16.9K

// source tiles: 16384 src rows = 2MB fp16 (L2-resident with stream headroom)
constexpr int TILE_SHIFT = 14;
constexpr int T_USER_TAB = 7;   // ceil(100000/16384): tiles of the user table
constexpr int T_ITEM_TAB = 4;   // ceil(50000/16384):  tiles of the item table

constexpr int P1_EDGES   = 8192;
constexpr int P1_THREADS = 512;
constexpr int P1_EPT     = P1_EDGES / P1_THREADS;  // 16
constexpr int P2_THREADS = 512;
constexpr int P2_BINS    = SB_ROWS * 8;            // 2048 (row, tile) bins

constexpr int SPMM_BLOCKS  = 512;   // x512 thr = 4096 waves, 2 blk/CU: resident
constexpr int SPMM_THREADS = 512;
constexpr int RPW_USER = (N_USERS + 4095) / 4096;  // 25 rows/wave
constexpr int RPW_ITEM = (N_ITEMS + 4095) / 4096;  // 13 rows/wave
constexpr int N_BAR = 32;

// ---------------- output layer 0 ----------------
__global__ void init_layer0(const float* __restrict__ uemb,
                            const float* __restrict__ iemb,
                            float* __restrict__ out) {
    long long idx = (long long)blockIdx.x * blockDim.x + threadIdx.x;
    if (idx < NUF) out[idx] = uemb[idx];
    if (idx < NIF) out[3 * NUF + idx] = iemb[idx];
}

// Tier T2: layer0 copy + fp16 conversion in one pass (h0 in ws, no alias).
__global__ void init_layer0_fused(const float* __restrict__ uemb,
                                  const float* __restrict__ iemb,
                                  float* __restrict__ out,
                                  _Float16* __restrict__ h0u,
                                  _Float16* __restrict__ h0i) {
    long long idx = ((long long)blockIdx.x * blockDim.x + threadIdx.x) * 4;
    if (idx < NUF) {
        float4 v = *(const float4*)(uemb + idx);
        *(float4*)(out + idx) = v;
        _Float16 h4[4] = {(_Float16)v.x, (_Float16)v.y, (_Float16)v.z, (_Float16)v.w};
        *(uint2*)(h0u + idx) = *(const uint2*)h4;
    }
    if (idx < NIF) {
        float4 v = *(const float4*)(iemb + idx);
        *(float4*)(out + 3 * NUF + idx) = v;
        _Float16 h4[4] = {(_Float16)v.x, (_Float16)v.y, (_Float16)v.z, (_Float16)v.w};
        *(uint2*)(h0i + idx) = *(const uint2*)h4;
    }
}

// Fallback-only: seed layers 1,2 with ALPHA*emb0.
__global__ void seed_alpha(const float* __restrict__ uemb,
                           const float* __restrict__ iemb,
                           float* __restrict__ out) {
    long long idx = (long long)blockIdx.x * blockDim.x + threadIdx.x;
    if (idx < NUF) {
        float av = ALPHA * uemb[idx];
        out[NUF + idx] = av;
        out[2 * NUF + idx] = av;
    }
    if (idx < NIF) {
        float av = ALPHA * iemb[idx];
        out[3 * NUF + NIF + idx] = av;
        out[3 * NUF + 2 * NIF + idx] = av;
    }
}

// ---------------- bucket cursors + barrier slots ----------------
__global__ void init_misc(int* __restrict__ sbcur, int* __restrict__ bar) {
    int t = blockIdx.x * blockDim.x + threadIdx.x;
    if (t < NSB) sbcur[t] = t * CAP;
    if (t < N_BAR) bar[t] = 0;
}

// After phase1: counts = sbcur[t] - t*CAP; exclusive scan -> sbstart.
__global__ void count_scan(const int* __restrict__ sbcur, int* __restrict__ sbstart) {
    __shared__ int sh[1024];
    int t = threadIdx.x;
    int v = (t < NSB) ? (sbcur[t] - t * CAP) : 0;
    sh[t] = v;
    __syncthreads();
    for (int off = 1; off < 1024; off <<= 1) {
        int x = (t >= off) ? sh[t - off] : 0;
        __syncthreads();
        sh[t] += x;
        __syncthreads();
    }
    if (t < NSB) {
        sbstart[t] = sh[t] - v;
        if (t == NSB - 1) sbstart[NSB] = sh[t];
    }
}

// ---------------- phase 1: bucketed bin-sort, coalesced run writes ----------
// scratch entry: (local_row << 17) | src   (local_row < 256, src < 2^17)
__global__ void phase1_binsort(const int* __restrict__ eu, const int* __restrict__ ei,
                               int* __restrict__ sbcur, unsigned* __restrict__ scratch) {
    __shared__ unsigned buf[2 * P1_EDGES];  // 64 KB
    __shared__ int hist[NSB];
    __shared__ int excl[NSB];
    __shared__ int gbase[NSB];
    __shared__ int psc[P1_THREADS];
    int t = threadIdx.x;
    int wv = t >> 6;
    int lane = t & 63;
    int nchunks = (E_EDGES + P1_EDGES - 1) / P1_EDGES;
    for (int c = blockIdx.x; c < nchunks; c += gridDim.x) {
        int lo = c * P1_EDGES;
        for (int r = t; r < NSB; r += P1_THREADS) hist[r] = 0;
        __syncthreads();
        unsigned sbr[2 * P1_EPT];
        unsigned val[2 * P1_EPT];
#pragma unroll
        for (int k = 0; k < P1_EPT; k++) {
            int e = lo + k * P1_THREADS + t;
            if (e < E_EDGES) {
                int u = __builtin_nontemporal_load(eu + e);
                int i = __builtin_nontemporal_load(ei + e);
                int r0 = u;
                int r1 = N_USERS + i;
                int sb0 = r0 >> SB_SHIFT;
                int sb1 = r1 >> SB_SHIFT;
                int rk0 = atomicAdd(&hist[sb0], 1);
                int rk1 = atomicAdd(&hist[sb1], 1);
                sbr[2 * k]     = ((unsigned)sb0 << 16) | (unsigned)rk0;
                val[2 * k]     = ((unsigned)(r0 & (SB_ROWS - 1)) << 17) | (unsigned)i;
                sbr[2 * k + 1] = ((unsigned)sb1 << 16) | (unsigned)rk1;
                val[2 * k + 1] = ((unsigned)(r1 & (SB_ROWS - 1)) << 17) | (unsigned)u;
            } else {
                sbr[2 * k]     = 0xFFFFFFFFu;
                sbr[2 * k + 1] = 0xFFFFFFFFu;
            }
        }
        __syncthreads();
        int a = (2 * t < NSB) ? hist[2 * t] : 0;
        int b = (2 * t + 1 < NSB) ? hist[2 * t + 1] : 0;
        psc[t] = a + b;
        __syncthreads();
        for (int off = 1; off < P1_THREADS; off <<= 1) {
            int x = (t >= off) ? psc[t - off] : 0;
            __syncthreads();
            psc[t] += x;
            __syncthreads();
        }
        int e0 = psc[t] - (a + b);
        if (2 * t < NSB)     excl[2 * t] = e0;
        if (2 * t + 1 < NSB) excl[2 * t + 1] = e0 + a;
        for (int r = t; r < NSB; r += P1_THREADS) {
            int cnt = hist[r];
            gbase[r] = cnt ? atomicAdd(&sbcur[r], cnt) : 0;
        }
        __syncthreads();
#pragma unroll
        for (int k = 0; k < 2 * P1_EPT; k++) {
            if (sbr[k] != 0xFFFFFFFFu) {
                int sb = (int)(sbr[k] >> 16);
                int rk = (int)(sbr[k] & 0xFFFFu);
                buf[excl[sb] + rk] = val[k];
            }
        }
        __syncthreads();
        for (int r = wv; r < NSB; r += P1_THREADS / 64) {
            int cnt  = hist[r];
            int base = gbase[r];
            int off  = excl[r];
            int cap_hi = (r + 1) * CAP;
            for (int k = lane; k < cnt; k += 64) {
                int p = base + k;
                if (p < cap_hi)  // OOB guard (never triggers: 32-sigma)
                    scratch[p] = buf[off + k];
            }
        }
        __syncthreads();
    }
}

// ---------------- phase 2: (row,tile) counting sort -> bnd[] + col[] --------
// bnd[crow*8 + t] = start of tile-t segment of row crow; bnd[N_ROWS*8] = 2E
// (falls out of the last bucket's empty bins). col sorted by (row, tile).
__global__ void phase2_fused(const unsigned* __restrict__ scratch,
                             const int* __restrict__ sbcur,
                             const int* __restrict__ sbstart,
                             int* __restrict__ bnd, int* __restrict__ col) {
    __shared__ unsigned buf[CAP];        // 80 KB
    __shared__ int hist[P2_BINS];        // 8 KB
    __shared__ int psc[P2_THREADS];      // 2 KB
    int sb = blockIdx.x;
    int t = threadIdx.x;
    int lo = sb * CAP;
    int n  = sbcur[sb] - lo;
    if (n > CAP) n = CAP;                // guard (never triggers)
    int out_lo = sbstart[sb];
    for (int k = t; k < P2_BINS; k += P2_THREADS) hist[k] = 0;
    __syncthreads();
    // pass 1: (row, tile) histogram
    for (int idx = t; idx < n; idx += P2_THREADS) {
        unsigned e = scratch[lo + idx];
        int key = (int)(e >> 17) * 8 + (int)((e & 0x1FFFFu) >> TILE_SHIFT);
        atomicAdd(&hist[key], 1);
    }
    __syncthreads();
    // scan 2048 bins: 4 per thread + 512-wide Hillis-Steele
    int b0 = hist[4 * t], b1 = hist[4 * t + 1];
    int b2 = hist[4 * t + 2], b3 = hist[4 * t + 3];
    int s4 = b0 + b1 + b2 + b3;
    psc[t] = s4;
    __syncthreads();
    for (int off = 1; off < P2_THREADS; off <<= 1) {
        int x = (t >= off) ? psc[t - off] : 0;
        __syncthreads();
        psc[t] += x;
        __syncthreads();
    }
    int base = psc[t] - s4;
    int e0 = base, e1 = base + b0, e2 = e1 + b1, e3 = e2 + b2;
    // write bnd (global bin index = sb*2048 + k) and turn hist into cursors
    long long gb = (long long)sb * P2_BINS + 4 * t;
    bnd[gb + 0] = out_lo + e0;
    bnd[gb + 1] = out_lo + e1;
    bnd[gb + 2] = out_lo + e2;
    bnd[gb + 3] = out_lo + e3;
    hist[4 * t]     = e0;
    hist[4 * t + 1] = e1;
    hist[4 * t + 2] = e2;
    hist[4 * t + 3] = e3;
    __syncthreads();
    // pass 2: rank via LDS cursor, scatter into LDS
    for (int idx = t; idx < n; idx += P2_THREADS) {
        unsigned e = scratch[lo + idx];
        int key = (int)(e >> 17) * 8 + (int)((e & 0x1FFFFu) >> TILE_SHIFT);
        int p = atomicAdd(&hist[key], 1);
        buf[p] = e & 0x1FFFFu;
    }
    __syncthreads();
    // pass 3: stream out (coalesced sequential stores)
    for (int k = t; k < n; k += P2_THREADS)
        col[out_lo + k] = (int)buf[k];
}

// ---------------- emb0 -> fp16 tables (tier T1: h0 in dead u2) ---------------
__global__ void emb_to_half(const float* __restrict__ uemb,
                            const float* __restrict__ iemb,
                            _Float16* __restrict__ hu, _Float16* __restrict__ hi) {
    long long idx = ((long long)blockIdx.x * blockDim.x + threadIdx.x) * 4;
    if (idx < NUF) {
        float4 v = *(const float4*)(uemb + idx);
        _Float16 h4[4] = {(_Float16)v.x, (_Float16)v.y, (_Float16)v.z, (_Float16)v.w};
        *(uint2*)(hu + idx) = *(const uint2*)h4;
    } else if (idx < NUF + NIF) {
        long long k = idx - NUF;
        float4 v = *(const float4*)(iemb + k);
        _Float16 h4[4] = {(_Float16)v.x, (_Float16)v.y, (_Float16)v.z, (_Float16)v.w};
        *(uint2*)(hi + k) = *(const uint2*)h4;
    }
}

// ---------------- bounded-spin grid barrier (perf-only) ----------------------
__device__ __forceinline__ void grid_bar(int* __restrict__ bar, int slot) {
    if (threadIdx.x == 0) {
        __hip_atomic_fetch_add(bar + slot, 1, __ATOMIC_RELAXED,
                               __HIP_MEMORY_SCOPE_AGENT);
        int spins = 0;
        while (__hip_atomic_load(bar + slot, __ATOMIC_RELAXED,
                                 __HIP_MEMORY_SCOPE_AGENT) < SPMM_BLOCKS &&
               spins < (1 << 15)) {
            __builtin_amdgcn_s_sleep(4);
            ++spins;
        }
    }
    __syncthreads();
}

// ---------------- tiled pull SPMM (co-resident grid) -------------------------
// Each wave owns RPW rows; acc in registers; tiles outermost with a grid
// barrier between -> concurrent gather footprint == one 2MB source tile.
template <int RPW, int TMAX, int ROW_BASE, int NROWS>
__global__ __launch_bounds__(SPMM_THREADS, 4)
void spmm_tiled(const int* __restrict__ bnd, const int* __restrict__ col,
                const _Float16* __restrict__ hsrc,
                const _Float16* __restrict__ e0h, const float* __restrict__ e0f,
                float* __restrict__ dst, _Float16* __restrict__ hdst,
                int* __restrict__ bar, int bar_base) {
    int gtid = blockIdx.x * SPMM_THREADS + threadIdx.x;
    int wave = gtid >> 6, lane = gtid & 63;
    int r0 = wave * RPW;
    float acc[RPW];
#pragma unroll
    for (int r = 0; r < RPW; ++r) acc[r] = 0.f;
    for (int t = 0; t < TMAX; ++t) {
#pragma unroll
        for (int r = 0; r < RPW; ++r) {
            int row = r0 + r;
            if (row < NROWS) {
                int crow = ROW_BASE + row;
                int s = __builtin_amdgcn_readfirstlane(bnd[crow * 8 + t]);
                int e = __builtin_amdgcn_readfirstlane(bnd[crow * 8 + t + 1]);
                float a = acc[r];
                int j = s;
                for (; j + 4 <= e; j += 4) {
                    int c0 = __builtin_nontemporal_load(col + j);
                    int c1 = __builtin_nontemporal_load(col + j + 1);
                    int c2 = __builtin_nontemporal_load(col + j + 2);
                    int c3 = __builtin_nontemporal_load(col + j + 3);
                    float g0 = (float)hsrc[((long long)c0 << 6) + lane];
                    float g1 = (float)hsrc[((long long)c1 << 6) + lane];
                    float g2 = (float)hsrc[((long long)c2 << 6) + lane];
                    float g3 = (float)hsrc[((long long)c3 << 6) + lane];
                    a += (g0 + g1) + (g2 + g3);
                }
                for (; j < e; ++j) {
                    int c = __builtin_nontemporal_load(col + j);
                    a += (float)hsrc[((long long)c << 6) + lane];
                }
                acc[r] = a;
            }
        }
        if (t < TMAX - 1) grid_bar(bar, bar_base + t);
    }
#pragma unroll
    for (int r = 0; r < RPW; ++r) {
        int row = r0 + r;
        if (row < NROWS) {
            int crow = ROW_BASE + row;
            int st = __builtin_amdgcn_readfirstlane(bnd[crow * 8]);
            int en = __builtin_amdgcn_readfirstlane(bnd[(crow + 1) * 8]);
            int len = en - st;
            float scale = (len > 0) ? 1.0f / (float)len : 0.0f;
            long long li = ((long long)row << 6) + lane;
            float e0v = e0h ? (float)e0h[li] : e0f[li];
            float res = scale * acc[r] + ALPHA * e0v;
            __builtin_nontemporal_store(res, dst + li);
            if (hdst) hdst[li] = (_Float16)res;
        }
    }
}

// ---------------- untiled fallbacks (tier B), bnd-indexed --------------------
__device__ __forceinline__ void pull_row_h2(const int* __restrict__ bnd,
                                            const int* __restrict__ col,
                                            const _Float16* __restrict__ hsrc,
                                            const _Float16* __restrict__ e0h,
                                            const float* __restrict__ e0f,
                                            float* __restrict__ dst,
                                            _Float16* __restrict__ hdst,
                                            int comb_row, int local_row, int lane) {
    int start = __builtin_amdgcn_readfirstlane(bnd[comb_row * 8]);
    int end   = __builtin_amdgcn_readfirstlane(bnd[(comb_row + 1) * 8]);
    int len = end - start;
    float scale = (len > 0) ? 1.0f / (float)len : 0.0f;
    float acc0 = 0.f, acc1 = 0.f, acc2 = 0.f, acc3 = 0.f;
    int j = start;
    for (; j + 8 <= end; j += 8) {
        int c0 = __builtin_nontemporal_load(col + j + 0);
        int c1 = __builtin_nontemporal_load(col + j + 1);
        int c2 = __builtin_nontemporal_load(col + j + 2);
        int c3 = __builtin_nontemporal_load(col + j + 3);
        int c4 = __builtin_nontemporal_load(col + j + 4);
        int c5 = __builtin_nontemporal_load(col + j + 5);
        int c6 = __builtin_nontemporal_load(col + j + 6);
        int c7 = __builtin_nontemporal_load(col + j + 7);
        acc0 += (float)hsrc[((long long)c0 << 6) + lane];
        acc1 += (float)hsrc[((long long)c1 << 6) + lane];
        acc2 += (float)hsrc[((long long)c2 << 6) + lane];
        acc3 += (float)hsrc[((long long)c3 << 6) + lane];
        acc0 += (float)hsrc[((long long)c4 << 6) + lane];
        acc1 += (float)hsrc[((long long)c5 << 6) + lane];
        acc2 += (float)hsrc[((long long)c6 << 6) + lane];
        acc3 += (float)hsrc[((long long)c7 << 6) + lane];
    }
    for (; j < end; j++) {
        int c = __builtin_nontemporal_load(col + j);
        acc0 += (float)hsrc[((long long)c << 6) + lane];
    }
    long long li = ((long long)local_row << 6) + lane;
    float e0 = e0h ? (float)e0h[li] : e0f[li];
    float res = scale * ((acc0 + acc1) + (acc2 + acc3)) + ALPHA * e0;
    __builtin_nontemporal_store(res, dst + li);
    if (hdst) hdst[li] = (_Float16)res;
}

__global__ void spmm_user_h(const int* __restrict__ bnd, const int* __restrict__ col,
                            const _Float16* __restrict__ hsrc_item,
                            const _Float16* __restrict__ e0h,
                            const float* __restrict__ e0f,
                            float* __restrict__ out_user,
                            _Float16* __restrict__ hout_user) {
    long long gtid = (long long)blockIdx.x * blockDim.x + threadIdx.x;
    int wave = (int)(gtid >> 6);
    int lane = (int)(gtid & 63);
    if (wave >= N_USERS) return;
    pull_row_h2(bnd, col, hsrc_item, e0h, e0f, out_user, hout_user,
                wave, wave, lane);
}

__global__ void spmm_item_h(const int* __restrict__ bnd, const int* __restrict__ col,
                            const _Float16* __restrict__ hsrc_user,
                            const _Float16* __restrict__ e0h,
                            const float* __restrict__ e0f,
                            float* __restrict__ out_item,
                            _Float16* __restrict__ hout_item) {
    long long gtid = (long long)blockIdx.x * blockDim.x + threadIdx.x;
    int wave = (int)(gtid >> 6);
    int lane = (int)(gtid & 63);
    if (wave >= N_ITEMS) return;
    pull_row_h2(bnd, col, hsrc_user, e0h, e0f, out_item, hout_item,
                N_USERS + wave, wave, lane);
}

__global__ void spmm_pull_f32(const int* __restrict__ bnd, const int* __restrict__ col,
                              const float* __restrict__ src_user,
                              const float* __restrict__ src_item,
                              const float* __restrict__ uemb,
                              const float* __restrict__ iemb,
                              float* __restrict__ out_user,
                              float* __restrict__ out_item) {
    long long gtid = (long long)blockIdx.x * blockDim.x + threadIdx.x;
    int wave = (int)(gtid >> 6);
    int lane = (int)(gtid & 63);
    if (wave >= N_ROWS) return;
    const float* src; const float* emb0; float* dst; int r;
    if (wave < N_USERS) {
        r = wave; src = src_item; emb0 = uemb; dst = out_user;
    } else {
        r = wave - N_USERS; src = src_user; emb0 = iemb; dst = out_item;
    }
    int start = __builtin_amdgcn_readfirstlane(bnd[wave * 8]);
    int end   = __builtin_amdgcn_readfirstlane(bnd[(wave + 1) * 8]);
    int len = end - start;
    float scale = (len > 0) ? 1.0f / (float)len : 0.0f;
    float acc0 = 0.f, acc1 = 0.f, acc2 = 0.f, acc3 = 0.f;
    int j = start;
    for (; j + 4 <= end; j += 4) {
        int c0 = col[j + 0], c1 = col[j + 1], c2 = col[j + 2], c3 = col[j + 3];
        acc0 += src[((long long)c0 << 6) + lane];
        acc1 += src[((long long)c1 << 6) + lane];
        acc2 += src[((long long)c2 << 6) + lane];
        acc3 += src[((long long)c3 << 6) + lane];
    }
    for (; j < end; j++) {
        int c = col[j];
        acc0 += src[((long long)c << 6) + lane];
    }
    float res = scale * ((acc0 + acc1) + (acc2 + acc3))
              + ALPHA * emb0[((long long)r << 6) + lane];
    dst[((long long)r << 6) + lane] = res;
}

// ---------------- fallback (atomic push) ----------------
__global__ void spmm_layer_atomic(const float* __restrict__ a_ui,
                                  const float* __restrict__ a_iu,
                                  const int* __restrict__ edge_u,
                                  const int* __restrict__ edge_i,
                                  const float* __restrict__ src_user,
                                  const float* __restrict__ src_item,
                                  float* __restrict__ dst_user,
                                  float* __restrict__ dst_item) {
    long long gtid = (long long)blockIdx.x * blockDim.x + threadIdx.x;
    long long wave = gtid >> 6;
    int lane = (int)(gtid & 63);
    if (wave < (long long)E_EDGES) {
        int e = (int)wave;
        int u = edge_u[e];
        int i = edge_i[e];
        float x = a_ui[e] * src_item[(long long)i * D + lane];
        __hip_atomic_fetch_add(dst_user + (long long)u * D + lane, x,
                               __ATOMIC_RELAXED, __HIP_MEMORY_SCOPE_AGENT);
    } else if (wave < 2LL * E_EDGES) {
        int e = (int)(wave - E_EDGES);
        int u = edge_u[e];
        int i = edge_i[e];
        float x = a_iu[e] * src_user[(long long)u * D + lane];
        __hip_atomic_fetch_add(dst_item + (long long)i * D + lane, x,
                               __ATOMIC_RELAXED, __HIP_MEMORY_SCOPE_AGENT);
    }
}

extern "C" void kernel_launch(void* const* d_in, const int* in_sizes, int n_in,
                              void* d_out, int out_size, void* d_ws, size_t ws_size,
                              hipStream_t stream) {
    const float* uemb   = (const float*)d_in[0];
    const float* iemb   = (const float*)d_in[1];
    const float* a_ui   = (const float*)d_in[2];
    const float* a_iu   = (const float*)d_in[3];
    const int*   edge_u = (const int*)d_in[4];
    const int*   edge_i = (const int*)d_in[5];
    float* out = (float*)d_out;

    float* u1 = out + NUF;
    float* u2 = out + 2 * NUF;
    float* i1 = out + 3 * NUF + NIF;
    float* i2 = out + 3 * NUF + 2 * NIF;

    // Padded bucketed scratch aliases u1+u2 (dead until spmm layers):
    // NSB*CAP = 12,001,280 u32 <= 12.8M floats.
    unsigned* scratch = (unsigned*)u1;

    size_t bnd_ints  = (size_t)NSB * P2_BINS + 8;
    size_t base_ints = N_BAR + NSB + (NSB + 1) + bnd_ints + 2 * (size_t)E_EDGES;
    size_t need_csr = base_ints * 4 + 64;
    size_t need_t1  = need_csr + (size_t)(NUF + NIF) * 2;  // + h1
    size_t need_t2  = need_t1 + (size_t)(NUF + NIF) * 2;   // + h0 in ws
    bool csr = ws_size >= need_csr;
    bool t1  = ws_size >= need_t1;
    bool t2  = ws_size >= need_t2;

    if (csr) {
        int* w = (int*)d_ws;
        int* bar     = w;  w += N_BAR;
        int* sbcur   = w;  w += NSB;
        int* sbstart = w;  w += NSB + 1;
        int* bnd     = w;  w += bnd_ints;
        int* col     = w;  w += 2 * E_EDGES;
        _Float16* h1u = (_Float16*)w;            // tier T1+
        _Float16* h1i = h1u + NUF;
        _Float16* h0u = t2 ? (h1i + NIF)         // T2: h0 in ws
                           : (_Float16*)u2;      // T1/B: h0 in dead u2
        _Float16* h0i = h0u + NUF;

        if (t2) {
            const long long quads = NUF / 4;
            const int blocks = (int)((quads + 255) / 256);
            init_layer0_fused<<<blocks, 256, 0, stream>>>(uemb, iemb, out,
                                                          h0u, h0i);
        } else {
            const int threads = 256;
            const int blocks = (int)((NUF + threads - 1) / threads);
            init_layer0<<<blocks, threads, 0, stream>>>(uemb, iemb, out);
        }

        init_misc<<<3, 256, 0, stream>>>(sbcur, bar);
        const int p1_blocks = (E_EDGES + P1_EDGES - 1) / P1_EDGES;  // 391
        phase1_binsort<<<p1_blocks, P1_THREADS, 0, stream>>>(edge_u, edge_i,
                                                             sbcur, scratch);
        count_scan<<<1, 1024, 0, stream>>>(sbcur, sbstart);
        phase2_fused<<<NSB, P2_THREADS, 0, stream>>>(scratch, sbcur, sbstart,
                                                     bnd, col);
        if (!t2) {
            // scratch consumed; convert emb0 -> h0 into dead u2.
            const long long quads = (NUF + NIF) / 4;
            const int blocks = (int)((quads + 255) / 256);
            emb_to_half<<<blocks, 256, 0, stream>>>(uemb, iemb, h0u, h0i);
        }

        if (t1) {
            // layer 1: tiled fp16 gather + fp16 alpha; emit h1.
            spmm_tiled<RPW_USER, T_ITEM_TAB, 0, N_USERS>
                <<<SPMM_BLOCKS, SPMM_THREADS, 0, stream>>>(
                    bnd, col, h0i, h0u, nullptr, u1, h1u, bar, 0);
            spmm_tiled<RPW_ITEM, T_USER_TAB, N_USERS, N_ITEMS>
                <<<SPMM_BLOCKS, SPMM_THREADS, 0, stream>>>(
                    bnd, col, h0u, h0i, nullptr, i1, h1i, bar, 4);
            // layer 2: tiled fp16 gather from h1; alpha fp16 only if h0 in ws.
            const _Float16* a2u = t2 ? h0u : nullptr;
            const _Float16* a2i = t2 ? h0i : nullptr;
            spmm_tiled<RPW_USER, T_ITEM_TAB, 0, N_USERS>
                <<<SPMM_BLOCKS, SPMM_THREADS, 0, stream>>>(
                    bnd, col, h1i, a2u, uemb, u2, nullptr, bar, 12);
            spmm_tiled<RPW_ITEM, T_USER_TAB, N_USERS, N_ITEMS>
                <<<SPMM_BLOCKS, SPMM_THREADS, 0, stream>>>(
                    bnd, col, h1u, a2i, iemb, i2, nullptr, bar, 16);
        } else {
            // tier B: untiled fp16 L1 (h0 in u2), f32 L2.
            const int ublocks = (int)(((long long)N_USERS * 64 + 255) / 256);
            const int iblocks = (int)(((long long)N_ITEMS * 64 + 255) / 256);
            spmm_user_h<<<ublocks, 256, 0, stream>>>(bnd, col, h0i, h0u, nullptr,
                                                     u1, nullptr);
            spmm_item_h<<<iblocks, 256, 0, stream>>>(bnd, col, h0u, h0i, nullptr,
                                                     i1, nullptr);
            const long long total_threads = (long long)N_ROWS * 64;
            const int blocks = (int)((total_threads + 255) / 256);
            spmm_pull_f32<<<blocks, 256, 0, stream>>>(bnd, col, u1, i1,
                                                      uemb, iemb, u2, i2);
        }
    } else {
        {
            const int threads = 256;
            const int blocks = (int)((NUF + threads - 1) / threads);
            init_layer0<<<blocks, threads, 0, stream>>>(uemb, iemb, out);
            seed_alpha<<<blocks, threads, 0, stream>>>(uemb, iemb, out);
        }
        const int threads = 256;
        const long long total_threads = 2LL * E_EDGES * 64;
        const int blocks = (int)((total_threads + threads - 1) / threads);
        spmm_layer_atomic<<<blocks, threads, 0, stream>>>(a_ui, a_iu, edge_u, edge_i,
                                                          uemb, iemb, u1, i1);
        spmm_layer_atomic<<<blocks, threads, 0, stream>>>(a_ui, a_iu, edge_u, edge_i,
                                                          u1, i1, u2, i2);
    }
}

// Round 8
// 560.055 us; speedup vs baseline: 2.8070x; 2.8070x over previous
//
#include <hip/hip_runtime.h>

// LightGCN propagation, MI355X. Round 12.
// R11 post-mortem: source-tiling collapsed FETCH to compulsory 84MB but dur
// 87->385us (273 GB/s, VGPR 32): tiny 9-entry segments + dependent scalar bnd
// loads destroyed memory-level parallelism. FETCH reduction only pays at
// constant effective BW if concurrency is preserved. REVERTED.
// Build ledger: R8 direct-scatter phase1 rest=235us < R10 coalesced-run 280
// < R9 per-wave-hist 300 -> R8 build restored verbatim.
// R12 = R8 build + R10 split fp16 spmm + ONE lever: gather unroll 8->16.
// Concurrency arithmetic: item pass needs ~143 outstanding req/CU at 500ns;
// 24 waves x 8 = 192 ~= at the product -> latency-bound, not fabric-bound.
// 16 in-flight/wave should push toward BW. If dur unchanged: 3.7 TB/s is the
// random-128B ceiling; spmm closed.
//
// Inputs: [0] user_emb0 [100000,64] f32, [1] item_emb0 [50000,64] f32,
// [2] a_ui_vals [E] f32 (unused; ==1/deg_u), [3] a_iu_vals [E] f32 (unused),
// [4] edge_u [E] i32, [5] edge_i [E] i32.
// Output: user_layers [3,100000,64] then item_layers [3,50000,64], f32 flat.

constexpr int N_USERS = 100000;
constexpr int N_ITEMS = 50000;
constexpr int N_ROWS  = N_USERS + N_ITEMS;   // combined CSR rows
constexpr int D = 64;
constexpr int E_EDGES = 3200000;
constexpr float ALPHA = 0.1f;

constexpr long long NUF = (long long)N_USERS * D;  // 6,400,000
constexpr long long NIF = (long long)N_ITEMS * D;  // 3,200,000

// super-buckets: 256 combined rows each
constexpr int SB_SHIFT = 8;
constexpr int SB_ROWS  = 1 << SB_SHIFT;                       // 256
constexpr int NSB      = (N_ROWS + SB_ROWS - 1) >> SB_SHIFT;  // 586
constexpr int CAP      = 20480;  // static slots per bucket; worst count ~16.9K

constexpr int P1_EDGES   = 8192;
constexpr int P1_THREADS = 512;
constexpr int P1_EPT     = P1_EDGES / P1_THREADS;  // 16
constexpr int P2_THREADS = 512;

// ---------------- output layer 0 ----------------
__global__ void init_layer0(const float* __restrict__ uemb,
                            const float* __restrict__ iemb,
                            float* __restrict__ out) {
    long long idx = (long long)blockIdx.x * blockDim.x + threadIdx.x;
    if (idx < NUF) out[idx] = uemb[idx];
    if (idx < NIF) out[3 * NUF + idx] = iemb[idx];
}

// Tier T2: layer0 copy + fp16 conversion in one pass (h0 in ws, no alias).
__global__ void init_layer0_fused(const float* __restrict__ uemb,
                                  const float* __restrict__ iemb,
                                  float* __restrict__ out,
                                  _Float16* __restrict__ h0u,
                                  _Float16* __restrict__ h0i) {
    long long idx = ((long long)blockIdx.x * blockDim.x + threadIdx.x) * 4;
    if (idx < NUF) {
        float4 v = *(const float4*)(uemb + idx);
        *(float4*)(out + idx) = v;
        _Float16 h4[4] = {(_Float16)v.x, (_Float16)v.y, (_Float16)v.z, (_Float16)v.w};
        *(uint2*)(h0u + idx) = *(const uint2*)h4;
    }
    if (idx < NIF) {
        float4 v = *(const float4*)(iemb + idx);
        *(float4*)(out + 3 * NUF + idx) = v;
        _Float16 h4[4] = {(_Float16)v.x, (_Float16)v.y, (_Float16)v.z, (_Float16)v.w};
        *(uint2*)(h0i + idx) = *(const uint2*)h4;
    }
}

// Fallback-only: seed layers 1,2 with ALPHA*emb0.
__global__ void seed_alpha(const float* __restrict__ uemb,
                           const float* __restrict__ iemb,
                           float* __restrict__ out) {
    long long idx = (long long)blockIdx.x * blockDim.x + threadIdx.x;
    if (idx < NUF) {
        float av = ALPHA * uemb[idx];
        out[NUF + idx] = av;
        out[2 * NUF + idx] = av;
    }
    if (idx < NIF) {
        float av = ALPHA * iemb[idx];
        out[3 * NUF + NIF + idx] = av;
        out[3 * NUF + 2 * NIF + idx] = av;
    }
}

// ---------------- bucket cursors at static offsets ----------------
__global__ void init_sbcur(int* __restrict__ sbcur) {
    int t = blockIdx.x * blockDim.x + threadIdx.x;
    if (t < NSB) sbcur[t] = t * CAP;
}

// After phase1: counts = sbcur[t] - t*CAP; exclusive scan -> sbstart.
__global__ void count_scan(const int* __restrict__ sbcur, int* __restrict__ sbstart) {
    __shared__ int sh[1024];
    int t = threadIdx.x;
    int v = (t < NSB) ? (sbcur[t] - t * CAP) : 0;
    sh[t] = v;
    __syncthreads();
    for (int off = 1; off < 1024; off <<= 1) {
        int x = (t >= off) ? sh[t - off] : 0;
        __syncthreads();
        sh[t] += x;
        __syncthreads();
    }
    if (t < NSB) {
        sbstart[t] = sh[t] - v;
        if (t == NSB - 1) sbstart[NSB] = sh[t];
    }
}

// ---------------- phase 1: bucketed bin-sort (R8 direct-scatter) -------------
// scratch entry: (local_row << 17) | src   (local_row < 256, src < 2^17)
// scratch is bucketed at static offsets sb*CAP.
__global__ void phase1_binsort(const int* __restrict__ eu, const int* __restrict__ ei,
                               int* __restrict__ sbcur, unsigned* __restrict__ scratch) {
    __shared__ int hist[NSB];
    __shared__ int gbase[NSB];
    int t = threadIdx.x;
    int nchunks = (E_EDGES + P1_EDGES - 1) / P1_EDGES;
    for (int c = blockIdx.x; c < nchunks; c += gridDim.x) {
        int lo = c * P1_EDGES;
        for (int r = t; r < NSB; r += P1_THREADS) hist[r] = 0;
        __syncthreads();
        unsigned sbr[2 * P1_EPT];
        unsigned val[2 * P1_EPT];
#pragma unroll
        for (int k = 0; k < P1_EPT; k++) {
            int e = lo + k * P1_THREADS + t;
            if (e < E_EDGES) {
                int u = __builtin_nontemporal_load(eu + e);
                int i = __builtin_nontemporal_load(ei + e);
                int r0 = u;             // user combined row
                int r1 = N_USERS + i;   // item combined row
                int sb0 = r0 >> SB_SHIFT;
                int sb1 = r1 >> SB_SHIFT;
                int rk0 = atomicAdd(&hist[sb0], 1);
                int rk1 = atomicAdd(&hist[sb1], 1);
                sbr[2 * k]     = ((unsigned)sb0 << 16) | (unsigned)rk0;
                val[2 * k]     = ((unsigned)(r0 & (SB_ROWS - 1)) << 17) | (unsigned)i;
                sbr[2 * k + 1] = ((unsigned)sb1 << 16) | (unsigned)rk1;
                val[2 * k + 1] = ((unsigned)(r1 & (SB_ROWS - 1)) << 17) | (unsigned)u;
            } else {
                sbr[2 * k]     = 0xFFFFFFFFu;
                sbr[2 * k + 1] = 0xFFFFFFFFu;
            }
        }
        __syncthreads();
        for (int r = t; r < NSB; r += P1_THREADS) {
            int cnt = hist[r];
            gbase[r] = cnt ? atomicAdd(&sbcur[r], cnt) : 0;
        }
        __syncthreads();
#pragma unroll
        for (int k = 0; k < 2 * P1_EPT; k++) {
            if (sbr[k] != 0xFFFFFFFFu) {
                int sb = (int)(sbr[k] >> 16);
                int rk = (int)(sbr[k] & 0xFFFFu);
                int p  = gbase[sb] + rk;
                if (p < (sb + 1) * CAP)  // OOB guard (never triggers: 32-sigma)
                    scratch[p] = val[k];
            }
        }
        __syncthreads();
    }
}

// ---------------- phase 2: per-bucket LDS reorder -> row[] + streaming col[] --
__global__ void phase2_fused(const unsigned* __restrict__ scratch,
                             const int* __restrict__ sbcur,
                             const int* __restrict__ sbstart,
                             int* __restrict__ row, int* __restrict__ col) {
    __shared__ unsigned buf[CAP];
    __shared__ int hist[SB_ROWS];
    __shared__ int pscan[SB_ROWS];
    int sb = blockIdx.x;
    int t = threadIdx.x;
    int lo = sb * CAP;
    int n  = sbcur[sb] - lo;
    if (n > CAP) n = CAP;            // guard (never triggers)
    int out_lo = sbstart[sb];
    if (t < SB_ROWS) hist[t] = 0;
    __syncthreads();
    for (int idx = t; idx < n; idx += P2_THREADS)
        atomicAdd(&hist[scratch[lo + idx] >> 17], 1);
    __syncthreads();
    if (t < SB_ROWS) pscan[t] = hist[t];
    __syncthreads();
    for (int off = 1; off < SB_ROWS; off <<= 1) {
        int x = 0;
        if (t < SB_ROWS && t >= off) x = pscan[t - off];
        __syncthreads();
        if (t < SB_ROWS) pscan[t] += x;
        __syncthreads();
    }
    int excl = 0;
    if (t < SB_ROWS) {
        excl = pscan[t] - hist[t];
        int gr = (sb << SB_SHIFT) + t;
        if (gr <= N_ROWS) row[gr] = out_lo + excl;  // also covers row[N_ROWS]
    }
    __syncthreads();
    if (t < SB_ROWS) hist[t] = excl;  // becomes the write cursor
    __syncthreads();
    for (int idx = t; idx < n; idx += P2_THREADS) {
        unsigned e = scratch[lo + idx];
        int p = atomicAdd(&hist[e >> 17], 1);
        buf[p] = e & 0x1FFFFu;
    }
    __syncthreads();
    for (int k = t; k < n; k += P2_THREADS)
        col[out_lo + k] = (int)buf[k];
}

// ---------------- emb0 -> fp16 tables (tier T1/B: h0 in dead u2) -------------
__global__ void emb_to_half(const float* __restrict__ uemb,
                            const float* __restrict__ iemb,
                            _Float16* __restrict__ hu, _Float16* __restrict__ hi) {
    long long idx = ((long long)blockIdx.x * blockDim.x + threadIdx.x) * 4;
    if (idx < NUF) {
        float4 v = *(const float4*)(uemb + idx);
        _Float16 h4[4] = {(_Float16)v.x, (_Float16)v.y, (_Float16)v.z, (_Float16)v.w};
        *(uint2*)(hu + idx) = *(const uint2*)h4;
    } else if (idx < NUF + NIF) {
        long long k = idx - NUF;
        float4 v = *(const float4*)(iemb + k);
        _Float16 h4[4] = {(_Float16)v.x, (_Float16)v.y, (_Float16)v.z, (_Float16)v.w};
        *(uint2*)(hi + k) = *(const uint2*)h4;
    }
}

// ---------------- pull SPMM, fp16 gather, 16-deep in-flight ----------------
__device__ __forceinline__ void pull_row_h2(const int* __restrict__ row,
                                            const int* __restrict__ col,
                                            const _Float16* __restrict__ hsrc,
                                            const _Float16* __restrict__ e0h,
                                            const float* __restrict__ e0f,
                                            float* __restrict__ dst,
                                            _Float16* __restrict__ hdst,
                                            int comb_row, int local_row, int lane) {
    int start = __builtin_amdgcn_readfirstlane(row[comb_row]);
    int end   = __builtin_amdgcn_readfirstlane(row[comb_row + 1]);
    int len = end - start;
    float scale = (len > 0) ? 1.0f / (float)len : 0.0f;

    float acc0 = 0.f, acc1 = 0.f, acc2 = 0.f, acc3 = 0.f;
    int j = start;
    // 16 independent gathers in flight per wave (latency x concurrency lever)
    for (; j + 16 <= end; j += 16) {
        int c[16];
#pragma unroll
        for (int k = 0; k < 16; k++)
            c[k] = __builtin_nontemporal_load(col + j + k);
        float g[16];
#pragma unroll
        for (int k = 0; k < 16; k++)
            g[k] = (float)hsrc[((long long)c[k] << 6) + lane];
#pragma unroll
        for (int k = 0; k < 16; k += 4) {
            acc0 += g[k];
            acc1 += g[k + 1];
            acc2 += g[k + 2];
            acc3 += g[k + 3];
        }
    }
    for (; j + 8 <= end; j += 8) {
        int c0 = __builtin_nontemporal_load(col + j + 0);
        int c1 = __builtin_nontemporal_load(col + j + 1);
        int c2 = __builtin_nontemporal_load(col + j + 2);
        int c3 = __builtin_nontemporal_load(col + j + 3);
        int c4 = __builtin_nontemporal_load(col + j + 4);
        int c5 = __builtin_nontemporal_load(col + j + 5);
        int c6 = __builtin_nontemporal_load(col + j + 6);
        int c7 = __builtin_nontemporal_load(col + j + 7);
        acc0 += (float)hsrc[((long long)c0 << 6) + lane];
        acc1 += (float)hsrc[((long long)c1 << 6) + lane];
        acc2 += (float)hsrc[((long long)c2 << 6) + lane];
        acc3 += (float)hsrc[((long long)c3 << 6) + lane];
        acc0 += (float)hsrc[((long long)c4 << 6) + lane];
        acc1 += (float)hsrc[((long long)c5 << 6) + lane];
        acc2 += (float)hsrc[((long long)c6 << 6) + lane];
        acc3 += (float)hsrc[((long long)c7 << 6) + lane];
    }
    for (; j < end; j++) {
        int c = __builtin_nontemporal_load(col + j);
        acc0 += (float)hsrc[((long long)c << 6) + lane];
    }
    long long li = ((long long)local_row << 6) + lane;
    float e0 = e0h ? (float)e0h[li] : e0f[li];
    float res = scale * ((acc0 + acc1) + (acc2 + acc3)) + ALPHA * e0;
    __builtin_nontemporal_store(res, dst + li);
    if (hdst) hdst[li] = (_Float16)res;
}

// user rows only: gather from fp16 item table (6.4MB footprint).
__global__ void spmm_user_h(const int* __restrict__ row, const int* __restrict__ col,
                            const _Float16* __restrict__ hsrc_item,
                            const _Float16* __restrict__ e0h,
                            const float* __restrict__ e0f,
                            float* __restrict__ out_user,
                            _Float16* __restrict__ hout_user) {
    long long gtid = (long long)blockIdx.x * blockDim.x + threadIdx.x;
    int wave = (int)(gtid >> 6);
    int lane = (int)(gtid & 63);
    if (wave >= N_USERS) return;
    pull_row_h2(row, col, hsrc_item, e0h, e0f, out_user, hout_user,
                wave, wave, lane);
}

// item rows only: gather from fp16 user table (12.8MB footprint).
__global__ void spmm_item_h(const int* __restrict__ row, const int* __restrict__ col,
                            const _Float16* __restrict__ hsrc_user,
                            const _Float16* __restrict__ e0h,
                            const float* __restrict__ e0f,
                            float* __restrict__ out_item,
                            _Float16* __restrict__ hout_item) {
    long long gtid = (long long)blockIdx.x * blockDim.x + threadIdx.x;
    int wave = (int)(gtid >> 6);
    int lane = (int)(gtid & 63);
    if (wave >= N_ITEMS) return;
    pull_row_h2(row, col, hsrc_user, e0h, e0f, out_item, hout_item,
                N_USERS + wave, wave, lane);
}

// ---------------- pull SPMM, f32 gather (tier B layer 2) ----------------
__global__ void spmm_pull(const int* __restrict__ row, const int* __restrict__ col,
                          const float* __restrict__ src_user,
                          const float* __restrict__ src_item,
                          const float* __restrict__ uemb, const float* __restrict__ iemb,
                          float* __restrict__ out_user, float* __restrict__ out_item) {
    long long gtid = (long long)blockIdx.x * blockDim.x + threadIdx.x;
    int wave = (int)(gtid >> 6);
    int lane = (int)(gtid & 63);
    if (wave >= N_ROWS) return;
    const float* src; const float* emb0; float* dst; int r;
    if (wave < N_USERS) {
        r = wave; src = src_item; emb0 = uemb; dst = out_user;
    } else {
        r = wave - N_USERS; src = src_user; emb0 = iemb; dst = out_item;
    }
    int start = __builtin_amdgcn_readfirstlane(row[wave]);
    int end   = __builtin_amdgcn_readfirstlane(row[wave + 1]);
    int len = end - start;
    float scale = (len > 0) ? 1.0f / (float)len : 0.0f;
    float acc0 = 0.f, acc1 = 0.f, acc2 = 0.f, acc3 = 0.f;
    int j = start;
    for (; j + 8 <= end; j += 8) {
        int c0 = col[j + 0], c1 = col[j + 1], c2 = col[j + 2], c3 = col[j + 3];
        int c4 = col[j + 4], c5 = col[j + 5], c6 = col[j + 6], c7 = col[j + 7];
        acc0 += src[((long long)c0 << 6) + lane];
        acc1 += src[((long long)c1 << 6) + lane];
        acc2 += src[((long long)c2 << 6) + lane];
        acc3 += src[((long long)c3 << 6) + lane];
        acc0 += src[((long long)c4 << 6) + lane];
        acc1 += src[((long long)c5 << 6) + lane];
        acc2 += src[((long long)c6 << 6) + lane];
        acc3 += src[((long long)c7 << 6) + lane];
    }
    for (; j < end; j++) {
        int c = col[j];
        acc0 += src[((long long)c << 6) + lane];
    }
    float res = scale * ((acc0 + acc1) + (acc2 + acc3))
              + ALPHA * emb0[((long long)r << 6) + lane];
    dst[((long long)r << 6) + lane] = res;
}

// ---------------- fallback (atomic push) ----------------
__global__ void spmm_layer_atomic(const float* __restrict__ a_ui,
                                  const float* __restrict__ a_iu,
                                  const int* __restrict__ edge_u,
                                  const int* __restrict__ edge_i,
                                  const float* __restrict__ src_user,
                                  const float* __restrict__ src_item,
                                  float* __restrict__ dst_user,
                                  float* __restrict__ dst_item) {
    long long gtid = (long long)blockIdx.x * blockDim.x + threadIdx.x;
    long long wave = gtid >> 6;
    int lane = (int)(gtid & 63);
    if (wave < (long long)E_EDGES) {
        int e = (int)wave;
        int u = edge_u[e];
        int i = edge_i[e];
        float x = a_ui[e] * src_item[(long long)i * D + lane];
        __hip_atomic_fetch_add(dst_user + (long long)u * D + lane, x,
                               __ATOMIC_RELAXED, __HIP_MEMORY_SCOPE_AGENT);
    } else if (wave < 2LL * E_EDGES) {
        int e = (int)(wave - E_EDGES);
        int u = edge_u[e];
        int i = edge_i[e];
        float x = a_iu[e] * src_user[(long long)u * D + lane];
        __hip_atomic_fetch_add(dst_item + (long long)i * D + lane, x,
                               __ATOMIC_RELAXED, __HIP_MEMORY_SCOPE_AGENT);
    }
}

extern "C" void kernel_launch(void* const* d_in, const int* in_sizes, int n_in,
                              void* d_out, int out_size, void* d_ws, size_t ws_size,
                              hipStream_t stream) {
    const float* uemb   = (const float*)d_in[0];
    const float* iemb   = (const float*)d_in[1];
    const float* a_ui   = (const float*)d_in[2];
    const float* a_iu   = (const float*)d_in[3];
    const int*   edge_u = (const int*)d_in[4];
    const int*   edge_i = (const int*)d_in[5];
    float* out = (float*)d_out;

    float* u1 = out + NUF;
    float* u2 = out + 2 * NUF;
    float* i1 = out + 3 * NUF + NIF;
    float* i2 = out + 3 * NUF + 2 * NIF;

    // Padded bucketed scratch aliases u1+u2 (dead until spmm layers):
    // NSB*CAP = 12,001,280 u32 <= 12.8M floats.
    unsigned* scratch = (unsigned*)u1;

    size_t base_ints = (size_t)(N_ROWS + 1) + NSB + (NSB + 1) + 2 * (size_t)E_EDGES;
    size_t need_b  = base_ints * 4 + 64;
    size_t need_t1 = need_b + (size_t)(NUF + NIF) * 2;   // + h1
    size_t need_t2 = need_t1 + (size_t)(NUF + NIF) * 2;  // + h0 in ws
    bool tier_b  = ws_size >= need_b;
    bool tier_t1 = ws_size >= need_t1;
    bool tier_t2 = ws_size >= need_t2;

    if (tier_b) {
        int* w = (int*)d_ws;
        int* row     = w;  w += N_ROWS + 1;
        int* sbcur   = w;  w += NSB;
        int* sbstart = w;  w += NSB + 1;
        int* col     = w;  w += 2 * E_EDGES;
        _Float16* h1u = (_Float16*)w;            // tier T1+
        _Float16* h1i = h1u + NUF;
        _Float16* h0u = tier_t2 ? (h1i + NIF)    // T2: h0 in ws
                                : (_Float16*)u2; // T1/B: h0 in dead u2
        _Float16* h0i = h0u + NUF;

        if (tier_t2) {
            const long long quads = NUF / 4;
            const int blocks = (int)((quads + 255) / 256);
            init_layer0_fused<<<blocks, 256, 0, stream>>>(uemb, iemb, out,
                                                          h0u, h0i);
        } else {
            const int threads = 256;
            const int blocks = (int)((NUF + threads - 1) / threads);
            init_layer0<<<blocks, threads, 0, stream>>>(uemb, iemb, out);
        }

        init_sbcur<<<3, 256, 0, stream>>>(sbcur);
        const int p1_blocks = (E_EDGES + P1_EDGES - 1) / P1_EDGES;  // 391
        phase1_binsort<<<p1_blocks, P1_THREADS, 0, stream>>>(edge_u, edge_i,
                                                             sbcur, scratch);
        count_scan<<<1, 1024, 0, stream>>>(sbcur, sbstart);
        phase2_fused<<<NSB, P2_THREADS, 0, stream>>>(scratch, sbcur, sbstart,
                                                     row, col);
        if (!tier_t2) {
            // scratch consumed; convert emb0 -> h0 into dead u2.
            const long long quads = (NUF + NIF) / 4;
            const int blocks = (int)((quads + 255) / 256);
            emb_to_half<<<blocks, 256, 0, stream>>>(uemb, iemb, h0u, h0i);
        }

        const int ublocks = (int)(((long long)N_USERS * 64 + 255) / 256);  // 25000
        const int iblocks = (int)(((long long)N_ITEMS * 64 + 255) / 256);  // 12500
        if (tier_t1) {
            // layer 1: fp16 gather + fp16 alpha; emit h1.
            spmm_user_h<<<ublocks, 256, 0, stream>>>(row, col, h0i, h0u, nullptr,
                                                     u1, h1u);
            spmm_item_h<<<iblocks, 256, 0, stream>>>(row, col, h0u, h0i, nullptr,
                                                     i1, h1i);
            // layer 2: fp16 gather from h1; alpha fp16 only if h0 in ws (T2).
            const _Float16* a2u = tier_t2 ? h0u : nullptr;
            const _Float16* a2i = tier_t2 ? h0i : nullptr;
            spmm_user_h<<<ublocks, 256, 0, stream>>>(row, col, h1i, a2u, uemb,
                                                     u2, nullptr);
            spmm_item_h<<<iblocks, 256, 0, stream>>>(row, col, h1u, a2i, iemb,
                                                     i2, nullptr);
        } else {
            // tier B: layer 1 fp16 gather (no h1), layer 2 f32 gather.
            spmm_user_h<<<ublocks, 256, 0, stream>>>(row, col, h0i, h0u, nullptr,
                                                     u1, nullptr);
            spmm_item_h<<<iblocks, 256, 0, stream>>>(row, col, h0u, h0i, nullptr,
                                                     i1, nullptr);
            const long long total_threads = (long long)N_ROWS * 64;
            const int blocks = (int)((total_threads + 255) / 256);
            spmm_pull<<<blocks, 256, 0, stream>>>(row, col, u1, i1,
                                                  uemb, iemb, u2, i2);
        }
    } else {
        {
            const int threads = 256;
            const int blocks = (int)((NUF + threads - 1) / threads);
            init_layer0<<<blocks, threads, 0, stream>>>(uemb, iemb, out);
            seed_alpha<<<blocks, threads, 0, stream>>>(uemb, iemb, out);
        }
        const int threads = 256;
        const long long total_threads = 2LL * E_EDGES * 64;
        const int blocks = (int)((total_threads + threads - 1) / threads);
        spmm_layer_atomic<<<blocks, threads, 0, stream>>>(a_ui, a_iu, edge_u, edge_i,
                                                          uemb, iemb, u1, i1);
        spmm_layer_atomic<<<blocks, threads, 0, stream>>>(a_ui, a_iu, edge_u, edge_i,
                                                          u1, i1, u2, i2);
    }
}